// Round 6
// baseline (667.666 us; speedup 1.0000x reference)
//
#include <hip/hip_runtime.h>

#define HALO 10
#define SWD 76   // per-wave staged row width (74 used, padded even)

typedef float v2f __attribute__((ext_vector_type(2)));

// 1D Gaussian, sigma=1.5, 11 taps, normalized (compile-time constants;
// matches the reference's fp32 window to ~1e-7 -- far under threshold)
#define G0 0.00102838f
#define G1 0.00759871f
#define G2 0.03600077f
#define G3 0.10936069f
#define G4 0.21300556f
#define G5 0.26601176f
#define G6 G4
#define G7 G3
#define G8 G2
#define G9 G1
#define G10 G0

// one horizontal tap-pair into named accumulators
#define HT(QA, QB, W0, W1, HM, HS, HC)                                   \
    { v2f p0; p0.x = QA.x; p0.y = QB.x;                                   \
      HM += p0 * (W0); HS += p0 * p0 * (W0); HC += QA.x * QB.x * (W0);    \
      v2f p1; p1.x = QA.y; p1.y = QB.y;                                   \
      HM += p1 * (W1); HS += p1 * p1 * (W1); HC += QA.y * QB.y * (W1); }

// horizontal 11-tap conv of one staged row (parity-adjusted 12 taps)
#define HCONV(AP, BP, HM, HS, HC)                                         \
    { const v2f* pa = (const v2f*)&(AP)[e];                               \
      const v2f* pb = (const v2f*)&(BP)[e];                               \
      const v2f qa0 = pa[0], qa1 = pa[1], qa2 = pa[2],                    \
                qa3 = pa[3], qa4 = pa[4], qa5 = pa[5];                    \
      const v2f qb0 = pb[0], qb1 = pb[1], qb2 = pb[2],                    \
                qb3 = pb[3], qb4 = pb[4], qb5 = pb[5];                    \
      HM = (v2f){0.f, 0.f}; HS = (v2f){0.f, 0.f}; HC = 0.f;               \
      HT(qa0, qb0, w2_0,  w2_1,  HM, HS, HC)                              \
      HT(qa1, qb1, w2_2,  w2_3,  HM, HS, HC)                              \
      HT(qa2, qb2, w2_4,  w2_5,  HM, HS, HC)                              \
      HT(qa3, qb3, w2_6,  w2_7,  HM, HS, HC)                              \
      HT(qa4, qb4, w2_8,  w2_9,  HM, HS, HC)                              \
      HT(qa5, qb5, w2_10, w2_11, HM, HS, HC) }

// shift the 55-scalar vertical register and insert the new row
#define VSHIFT(NM, NS, NC)                                                \
    Hm0=Hm1; Hm1=Hm2; Hm2=Hm3; Hm3=Hm4; Hm4=Hm5; Hm5=Hm6;                 \
    Hm6=Hm7; Hm7=Hm8; Hm8=Hm9; Hm9=Hm10; Hm10=NM;                         \
    Hs0=Hs1; Hs1=Hs2; Hs2=Hs3; Hs3=Hs4; Hs4=Hs5; Hs5=Hs6;                 \
    Hs6=Hs7; Hs7=Hs8; Hs8=Hs9; Hs9=Hs10; Hs10=NS;                         \
    Hc0=Hc1; Hc1=Hc2; Hc2=Hc3; Hc3=Hc4; Hc4=Hc5; Hc5=Hc6;                 \
    Hc6=Hc7; Hc7=Hc8; Hc8=Hc9; Hc9=Hc10; Hc10=NC;

// vertical 11-tap combine + SSIM/CS accumulation for output row OROW
#define VOUT(OROW)                                                        \
    if ((OROW) >= 0 && (OROW) < n_out && colvalid) {                      \
        v2f vm = Hm0*G0; vm += Hm1*G1; vm += Hm2*G2; vm += Hm3*G3;        \
        vm += Hm4*G4; vm += Hm5*G5; vm += Hm6*G6; vm += Hm7*G7;           \
        vm += Hm8*G8; vm += Hm9*G9; vm += Hm10*G10;                       \
        v2f vs = Hs0*G0; vs += Hs1*G1; vs += Hs2*G2; vs += Hs3*G3;        \
        vs += Hs4*G4; vs += Hs5*G5; vs += Hs6*G6; vs += Hs7*G7;           \
        vs += Hs8*G8; vs += Hs9*G9; vs += Hs10*G10;                       \
        float vc = Hc0*G0; vc += Hc1*G1; vc += Hc2*G2; vc += Hc3*G3;      \
        vc += Hc4*G4; vc += Hc5*G5; vc += Hc6*G6; vc += Hc7*G7;           \
        vc += Hc8*G8; vc += Hc9*G9; vc += Hc10*G10;                       \
        const float mx = vm.x, my = vm.y;                                 \
        const float mu_x2 = mx * mx, mu_y2 = my * my, mu_xy = mx * my;    \
        const float sxq = vs.x - mu_x2, syq = vs.y - mu_y2;               \
        const float sxyv = vc - mu_xy;                                    \
        const float c1 = 1e-4f, c2 = 9e-4f;                               \
        const float cs = (2.f * sxyv + c2)                                \
                       * __builtin_amdgcn_rcpf(sxq + syq + c2);           \
        const float ssim = (2.f * mu_xy + c1)                             \
                         * __builtin_amdgcn_rcpf(mu_x2 + mu_y2 + c1) * cs;\
        ssim_sum += ssim; cs_sum += cs;                                   \
    }

// Wave-private row-streaming separable SSIM + fused 2x2 avg-pool.
// DOUBLE-ROW steps: rows i,i+1 per unrolled step (i parity static), loads
// for i+2,i+3 issued a full step before use. No local arrays anywhere in
// the hot path (SROA-before-unroll demotes runtime-indexed arrays: R3/R4).
__global__ __launch_bounds__(256, 4) void ssim_wave_kernel(
    const float* __restrict__ x, const float* __restrict__ y,
    float* __restrict__ xo, float* __restrict__ yo,
    float* __restrict__ acc, int H, int W, int ROWS, int do_pool)
{
    const int OH = H - HALO, OW = W - HALO;
    const int nc = blockIdx.z;
    const int tid = threadIdx.x;
    const int wave = tid >> 6, lane = tid & 63;
    const int col0 = blockIdx.x * 64;
    const int r0 = (blockIdx.y * 4 + wave) * ROWS;

    const int c = col0 + lane;
    const bool colvalid = (c < OW);
    const int cl = min(c, W - 1);
    const int chalo = min(col0 + 64 + lane, W - 1);

    const int n_out = min(ROWS, OH - r0);            // may be <= 0 (pool-only tail)
    const int poolrows = do_pool ? min(ROWS, H - r0) : 0;
    const int n_iter = max(n_out > 0 ? n_out + HALO : 0, poolrows);

    const float* xp = x + (size_t)nc * H * W;
    const float* yp = y + (size_t)nc * H * W;

    __shared__ float sA[4][2 * SWD];
    __shared__ float sB[4][2 * SWD];
    float* A0 = sA[wave];        float* B0 = sB[wave];
    float* A1 = sA[wave] + SWD;  float* B1 = sB[wave] + SWD;

    // parity-adjusted 12-tap weights as named scalars
    const int par = lane & 1;
    const float w2_0  = par ? 0.f : G0;
    const float w2_1  = par ? G0  : G1;
    const float w2_2  = par ? G1  : G2;
    const float w2_3  = par ? G2  : G3;
    const float w2_4  = par ? G3  : G4;
    const float w2_5  = par ? G4  : G5;
    const float w2_6  = par ? G5  : G6;
    const float w2_7  = par ? G6  : G7;
    const float w2_8  = par ? G7  : G8;
    const float w2_9  = par ? G8  : G9;
    const float w2_10 = par ? G9  : G10;
    const float w2_11 = par ? G10 : 0.f;
    const int e = lane & ~1;

    // vertical shift register (55 named scalars)
    v2f Hm0={0.f,0.f}, Hm1=Hm0, Hm2=Hm0, Hm3=Hm0, Hm4=Hm0, Hm5=Hm0,
        Hm6=Hm0, Hm7=Hm0, Hm8=Hm0, Hm9=Hm0, Hm10=Hm0;
    v2f Hs0=Hm0, Hs1=Hm0, Hs2=Hm0, Hs3=Hm0, Hs4=Hm0, Hs5=Hm0,
        Hs6=Hm0, Hs7=Hm0, Hs8=Hm0, Hs9=Hm0, Hs10=Hm0;
    float Hc0=0.f, Hc1=0.f, Hc2=0.f, Hc3=0.f, Hc4=0.f, Hc5=0.f,
          Hc6=0.f, Hc7=0.f, Hc8=0.f, Hc9=0.f, Hc10=0.f;

    float ssim_sum = 0.f, cs_sum = 0.f;

    // two staged rows in flight, all named scalars
    float cx0=0.f, cy0=0.f, hx0=0.f, hy0=0.f;   // row i
    float cx1=0.f, cy1=0.f, hx1=0.f, hy1=0.f;   // row i+1

    const int Wo = W >> 1;
    float* xop = xo + (size_t)nc * (H >> 1) * Wo + (col0 >> 1);
    float* yop = yo + (size_t)nc * (H >> 1) * Wo + (col0 >> 1);

    if (n_iter > 0) {
        {   // prologue: load rows r0, r0+1
            const float* rx0 = xp + (size_t)r0 * W;
            const float* ry0 = yp + (size_t)r0 * W;
            const int r1 = min(r0 + 1, H - 1);
            const float* rx1 = xp + (size_t)r1 * W;
            const float* ry1 = yp + (size_t)r1 * W;
            cx0 = rx0[cl]; cy0 = ry0[cl];
            cx1 = rx1[cl]; cy1 = ry1[cl];
            if (lane < HALO) {
                hx0 = rx0[chalo]; hy0 = ry0[chalo];
                hx1 = rx1[chalo]; hy1 = ry1[chalo];
            }
        }
        const int steps = (n_iter + 1) >> 1;
        const int nouter = (steps + 10) / 11;
        for (int t = 0; t < nouter; ++t) {
            const int ib = t * 22;
#pragma unroll
            for (int u = 0; u < 11; ++u) {
                const int i = ib + 2 * u;   // rows i, i+1 (i always even)

                // fused 2x2 avg-pool straight from the row registers
                if (do_pool && i < poolrows) {
                    const float s0x = cx0 + __shfl_xor(cx0, 1, 64);
                    const float s0y = cy0 + __shfl_xor(cy0, 1, 64);
                    const float s1x = cx1 + __shfl_xor(cx1, 1, 64);
                    const float s1y = cy1 + __shfl_xor(cy1, 1, 64);
                    if (par == 0) {
                        const int pr = (r0 + i) >> 1;
                        xop[(size_t)pr * Wo + (lane >> 1)] = 0.25f * (s0x + s1x);
                        yop[(size_t)pr * Wo + (lane >> 1)] = 0.25f * (s0y + s1y);
                    }
                }

                // stage rows i, i+1 into this wave's LDS slices
                A0[lane] = cx0; B0[lane] = cy0;
                A1[lane] = cx1; B1[lane] = cy1;
                if (lane < HALO) {
                    A0[64 + lane] = hx0; B0[64 + lane] = hy0;
                    A1[64 + lane] = hx1; B1[64 + lane] = hy1;
                }

                // issue loads for rows i+2, i+3 (consumed next step)
                float nx0, ny0, nhx0 = 0.f, nhy0 = 0.f;
                float nx1, ny1, nhx1 = 0.f, nhy1 = 0.f;
                {
                    const int r2 = min(r0 + i + 2, H - 1);
                    const int r3 = min(r0 + i + 3, H - 1);
                    const float* rx2 = xp + (size_t)r2 * W;
                    const float* ry2 = yp + (size_t)r2 * W;
                    const float* rx3 = xp + (size_t)r3 * W;
                    const float* ry3 = yp + (size_t)r3 * W;
                    nx0 = rx2[cl]; ny0 = ry2[cl];
                    nx1 = rx3[cl]; ny1 = ry3[cl];
                    if (lane < HALO) {
                        nhx0 = rx2[chalo]; nhy0 = ry2[chalo];
                        nhx1 = rx3[chalo]; nhy1 = ry3[chalo];
                    }
                }

                // horizontal conv of both rows
                v2f hma, hsa; float hca;
                v2f hmb, hsb; float hcb;
                HCONV(A0, B0, hma, hsa, hca)
                HCONV(A1, B1, hmb, hsb, hcb)

                // shift in row i -> output o = i-10
                VSHIFT(hma, hsa, hca)
                VOUT(i - HALO)
                // shift in row i+1 -> output o = i-9
                VSHIFT(hmb, hsb, hcb)
                VOUT(i - HALO + 1)

                // rotate prefetch registers (SSA copies, renamed away)
                cx0 = nx0; cy0 = ny0; hx0 = nhx0; hy0 = nhy0;
                cx1 = nx1; cy1 = ny1; hx1 = nhx1; hy1 = nhy1;
            }
        }
    }

    // wave-local reduction + one atomic pair per wave
#pragma unroll
    for (int off = 32; off > 0; off >>= 1) {
        ssim_sum += __shfl_down(ssim_sum, off, 64);
        cs_sum   += __shfl_down(cs_sum,   off, 64);
    }
    if (lane == 0) {
        atomicAdd(&acc[nc * 2 + 0], ssim_sum);
        atomicAdd(&acc[nc * 2 + 1], cs_sum);
    }
}

// Combine the 5 scales: prod_s val_s^{w_s}, mean over the 48 (n,c) pairs.
__global__ void finalize_kernel(const float* __restrict__ acc,
                                const float* __restrict__ weights,
                                float* __restrict__ out)
{
    int t = threadIdx.x;  // 64 threads
    float v = 0.f;
    if (t < 48) {
        float prod = 1.f;
#pragma unroll
        for (int s = 0; s < 5; ++s) {
            int O = (512 >> s) - HALO;
            float inv = 1.f / ((float)O * (float)O);
            float ssim = acc[s * 96 + t * 2 + 0] * inv;
            float cs   = acc[s * 96 + t * 2 + 1] * inv;
            float val = (s < 4) ? fmaxf(cs, 0.f) : ssim;  // mcs[:-1] + [ssim]
            prod *= powf(val, weights[s]);
        }
        v = prod;
    }
#pragma unroll
    for (int off = 32; off > 0; off >>= 1) v += __shfl_down(v, off, 64);
    if (t == 0) out[0] = v * (1.f / 48.f);
}

extern "C" void kernel_launch(void* const* d_in, const int* in_sizes, int n_in,
                              void* d_out, int out_size, void* d_ws, size_t ws_size,
                              hipStream_t stream) {
    const float* x = (const float*)d_in[0];       // (16,3,512,512)
    const float* y = (const float*)d_in[1];       // (16,3,512,512)
    const float* weights = (const float*)d_in[3]; // (5,)
    float* out = (float*)d_out;
    float* ws = (float*)d_ws;

    // workspace layout (floats):
    //   [0,480)   : acc[5 scales][48 nc][2]   (ssim_sum, cs_sum)
    //   [512, ..) : downsampled pyramid x/y per scale
    float* acc = ws;
    float* xs1 = ws + 512;
    float* ys1 = xs1 + (size_t)48 * 256 * 256;
    float* xs2 = ys1 + (size_t)48 * 256 * 256;
    float* ys2 = xs2 + (size_t)48 * 128 * 128;
    float* xs3 = ys2 + (size_t)48 * 128 * 128;
    float* ys3 = xs3 + (size_t)48 * 64 * 64;
    float* xs4 = ys3 + (size_t)48 * 64 * 64;
    float* ys4 = xs4 + (size_t)48 * 32 * 32;

    hipMemsetAsync(acc, 0, 480 * sizeof(float), stream);

    dim3 blk(256);
    // grid: (col strips of 64, row chunks of 4*ROWS, nc); 4 indep waves/block
    // scale 0: ROWS=32 -> 16 chunks -> 1536 blocks (16 waves/CU resident)
    ssim_wave_kernel<<<dim3(8, 4, 48), blk, 0, stream>>>(x, y, xs1, ys1, acc + 0 * 96, 512, 512, 32, 1);
    // scale 1: ROWS=16 -> 16 chunks -> 768 blocks
    ssim_wave_kernel<<<dim3(4, 4, 48), blk, 0, stream>>>(xs1, ys1, xs2, ys2, acc + 1 * 96, 256, 256, 16, 1);
    // scale 2: ROWS=8 -> 16 chunks -> 384 blocks
    ssim_wave_kernel<<<dim3(2, 4, 48), blk, 0, stream>>>(xs2, ys2, xs3, ys3, acc + 2 * 96, 128, 128, 8, 1);
    // scale 3: ROWS=8 -> 8 chunks -> 96 blocks
    ssim_wave_kernel<<<dim3(1, 2, 48), blk, 0, stream>>>(xs3, ys3, xs4, ys4, acc + 3 * 96, 64, 64, 8, 1);
    // scale 4: ROWS=6 -> 4 chunks -> 48 blocks, no pooling
    ssim_wave_kernel<<<dim3(1, 1, 48), blk, 0, stream>>>(xs4, ys4, nullptr, nullptr, acc + 4 * 96, 32, 32, 6, 0);

    finalize_kernel<<<dim3(1), dim3(64), 0, stream>>>(acc, weights, out);
}

// Round 7
// 351.305 us; speedup vs baseline: 1.9005x; 1.9005x over previous
//
#include <hip/hip_runtime.h>

#define HALO 10
#define SWD 76   // per-wave staged row width (74 used, padded even)

typedef float v2f __attribute__((ext_vector_type(2)));

// 1D Gaussian, sigma=1.5, 11 taps, normalized (compile-time constants;
// matches the reference's fp32 window to ~1e-7 -- far under threshold)
#define G0 0.00102838f
#define G1 0.00759871f
#define G2 0.03600077f
#define G3 0.10936069f
#define G4 0.21300556f
#define G5 0.26601176f
#define G6 G4
#define G7 G3
#define G8 G2
#define G9 G1
#define G10 G0

// one horizontal tap-pair: packed {x,y} means, squares, and cross term
#define HT(QA, QB, W0, W1)                                          \
    { v2f p0; p0.x = QA.x; p0.y = QB.x;                              \
      hm += p0 * (W0); hs += p0 * p0 * (W0); hc += QA.x * QB.x * (W0);\
      v2f p1; p1.x = QA.y; p1.y = QB.y;                              \
      hm += p1 * (W1); hs += p1 * p1 * (W1); hc += QA.y * QB.y * (W1); }

// Wave-private row-streaming separable SSIM + fused 2x2 avg-pool.
// ZERO local arrays in the hot path (SROA runs before unroll: any
// runtime-indexed local array gets demoted to scratch -- R3/R4 lesson).
// Vertical 11-tap conv is a 55-scalar named shift register.
// NOTE: __launch_bounds__ second arg MUST stay 3 -- (256,4) caps VGPR at 128
// and forces a 265 MB scratch spill (R6 regression).
__global__ __launch_bounds__(256, 3) void ssim_wave_kernel(
    const float* __restrict__ x, const float* __restrict__ y,
    float* __restrict__ xo, float* __restrict__ yo,
    float* __restrict__ acc, int H, int W, int ROWS, int do_pool)
{
    const int OH = H - HALO, OW = W - HALO;
    const int nc = blockIdx.z;
    const int tid = threadIdx.x;
    const int wave = tid >> 6, lane = tid & 63;
    const int col0 = blockIdx.x * 64;
    const int r0 = (blockIdx.y * 4 + wave) * ROWS;

    const int c = col0 + lane;
    const bool colvalid = (c < OW);
    const int cl = min(c, W - 1);
    const int chalo = min(col0 + 64 + lane, W - 1);

    const int n_out = min(ROWS, OH - r0);            // may be <= 0 (pool-only tail)
    const int poolrows = do_pool ? min(ROWS, H - r0) : 0;
    const int n_iter = max(n_out > 0 ? n_out + HALO : 0, poolrows);

    const float* xp = x + (size_t)nc * H * W;
    const float* yp = y + (size_t)nc * H * W;

    __shared__ float sA[4][SWD];
    __shared__ float sB[4][SWD];
    float* myA = sA[wave];
    float* myB = sB[wave];

    // parity-adjusted 12-tap weights as NAMED scalars
    const int par = lane & 1;
    const float w2_0  = par ? 0.f : G0;
    const float w2_1  = par ? G0  : G1;
    const float w2_2  = par ? G1  : G2;
    const float w2_3  = par ? G2  : G3;
    const float w2_4  = par ? G3  : G4;
    const float w2_5  = par ? G4  : G5;
    const float w2_6  = par ? G5  : G6;
    const float w2_7  = par ? G6  : G7;
    const float w2_8  = par ? G7  : G8;
    const float w2_9  = par ? G8  : G9;
    const float w2_10 = par ? G9  : G10;
    const float w2_11 = par ? G10 : 0.f;
    const int e = lane & ~1;

    // vertical shift register: slot j holds h-values of input row o+j
    v2f Hm0={0.f,0.f}, Hm1=Hm0, Hm2=Hm0, Hm3=Hm0, Hm4=Hm0, Hm5=Hm0,
        Hm6=Hm0, Hm7=Hm0, Hm8=Hm0, Hm9=Hm0, Hm10=Hm0;
    v2f Hs0=Hm0, Hs1=Hm0, Hs2=Hm0, Hs3=Hm0, Hs4=Hm0, Hs5=Hm0,
        Hs6=Hm0, Hs7=Hm0, Hs8=Hm0, Hs9=Hm0, Hs10=Hm0;
    float Hc0=0.f, Hc1=0.f, Hc2=0.f, Hc3=0.f, Hc4=0.f, Hc5=0.f,
          Hc6=0.f, Hc7=0.f, Hc8=0.f, Hc9=0.f, Hc10=0.f;

    float ssim_sum = 0.f, cs_sum = 0.f;

    // depth-1 prefetch, scalar registers only
    float vx = 0.f, vy = 0.f, hxv = 0.f, hyv = 0.f;
    float prevx = 0.f, prevy = 0.f;

    const int Wo = W >> 1;
    float* xop = xo + (size_t)nc * (H >> 1) * Wo + (col0 >> 1);
    float* yop = yo + (size_t)nc * (H >> 1) * Wo + (col0 >> 1);

    if (n_iter > 0) {
        {   // load row 0
            const float* rx = xp + (size_t)r0 * W;
            const float* ry = yp + (size_t)r0 * W;
            vx = rx[cl]; vy = ry[cl];
            if (lane < HALO) { hxv = rx[chalo]; hyv = ry[chalo]; }
        }
        const int NI = ((n_iter + 10) / 11) * 11;
        for (int ii = 0; ii < NI; ii += 11) {
#pragma unroll
            for (int u = 0; u < 11; ++u) {
                const int i = ii + u;

                // fused 2x2 avg-pool from the row registers
                if (do_pool && i < poolrows) {
                    float sx2 = vx + __shfl_xor(vx, 1, 64);
                    float sy2 = vy + __shfl_xor(vy, 1, 64);
                    if (i & 1) {
                        if (par == 0) {
                            const int pr = (r0 + i) >> 1;
                            xop[(size_t)pr * Wo + (lane >> 1)] = 0.25f * (prevx + sx2);
                            yop[(size_t)pr * Wo + (lane >> 1)] = 0.25f * (prevy + sy2);
                        }
                    } else { prevx = sx2; prevy = sy2; }
                }

                // stage row i into this wave's LDS slice (no barrier needed)
                myA[lane] = vx; myB[lane] = vy;
                if (lane < HALO) { myA[64 + lane] = hxv; myB[64 + lane] = hyv; }

                // issue loads for row i+1
                {
                    const int rr = min(r0 + i + 1, H - 1);
                    const float* rx = xp + (size_t)rr * W;
                    const float* ry = yp + (size_t)rr * W;
                    vx = rx[cl]; vy = ry[cl];
                    if (lane < HALO) { hxv = rx[chalo]; hyv = ry[chalo]; }
                }

                // horizontal 11-tap conv from 6 named float2 LDS loads
                const v2f* pa = (const v2f*)&myA[e];
                const v2f* pb = (const v2f*)&myB[e];
                const v2f qa0 = pa[0], qa1 = pa[1], qa2 = pa[2],
                          qa3 = pa[3], qa4 = pa[4], qa5 = pa[5];
                const v2f qb0 = pb[0], qb1 = pb[1], qb2 = pb[2],
                          qb3 = pb[3], qb4 = pb[4], qb5 = pb[5];
                v2f hm = {0.f, 0.f}, hs = {0.f, 0.f};
                float hc = 0.f;
                HT(qa0, qb0, w2_0,  w2_1)
                HT(qa1, qb1, w2_2,  w2_3)
                HT(qa2, qb2, w2_4,  w2_5)
                HT(qa3, qb3, w2_6,  w2_7)
                HT(qa4, qb4, w2_8,  w2_9)
                HT(qa5, qb5, w2_10, w2_11)

                // shift in row i (renamed away under the unroll)
                Hm0=Hm1; Hm1=Hm2; Hm2=Hm3; Hm3=Hm4; Hm4=Hm5; Hm5=Hm6;
                Hm6=Hm7; Hm7=Hm8; Hm8=Hm9; Hm9=Hm10; Hm10=hm;
                Hs0=Hs1; Hs1=Hs2; Hs2=Hs3; Hs3=Hs4; Hs4=Hs5; Hs5=Hs6;
                Hs6=Hs7; Hs7=Hs8; Hs8=Hs9; Hs9=Hs10; Hs10=hs;
                Hc0=Hc1; Hc1=Hc2; Hc2=Hc3; Hc3=Hc4; Hc4=Hc5; Hc5=Hc6;
                Hc6=Hc7; Hc7=Hc8; Hc8=Hc9; Hc9=Hc10; Hc10=hc;

                // output row o = i-10: slot j holds rows o..o+10
                const int o = i - HALO;
                if (o >= 0 && o < n_out && colvalid) {
                    v2f vm = Hm0*G0; vm += Hm1*G1; vm += Hm2*G2; vm += Hm3*G3;
                    vm += Hm4*G4; vm += Hm5*G5; vm += Hm6*G6; vm += Hm7*G7;
                    vm += Hm8*G8; vm += Hm9*G9; vm += Hm10*G10;
                    v2f vs = Hs0*G0; vs += Hs1*G1; vs += Hs2*G2; vs += Hs3*G3;
                    vs += Hs4*G4; vs += Hs5*G5; vs += Hs6*G6; vs += Hs7*G7;
                    vs += Hs8*G8; vs += Hs9*G9; vs += Hs10*G10;
                    float vc = Hc0*G0; vc += Hc1*G1; vc += Hc2*G2; vc += Hc3*G3;
                    vc += Hc4*G4; vc += Hc5*G5; vc += Hc6*G6; vc += Hc7*G7;
                    vc += Hc8*G8; vc += Hc9*G9; vc += Hc10*G10;

                    const float mx = vm.x, my = vm.y;
                    const float mu_x2 = mx * mx, mu_y2 = my * my, mu_xy = mx * my;
                    const float sxq = vs.x - mu_x2, syq = vs.y - mu_y2, sxyv = vc - mu_xy;
                    const float c1 = 1e-4f, c2 = 9e-4f;
                    const float cs = (2.f * sxyv + c2) * __builtin_amdgcn_rcpf(sxq + syq + c2);
                    const float ssim = (2.f * mu_xy + c1) * __builtin_amdgcn_rcpf(mu_x2 + mu_y2 + c1) * cs;
                    ssim_sum += ssim;
                    cs_sum += cs;
                }
            }
        }
    }

    // wave-local reduction + one atomic pair per wave
#pragma unroll
    for (int off = 32; off > 0; off >>= 1) {
        ssim_sum += __shfl_down(ssim_sum, off, 64);
        cs_sum   += __shfl_down(cs_sum,   off, 64);
    }
    if (lane == 0) {
        atomicAdd(&acc[nc * 2 + 0], ssim_sum);
        atomicAdd(&acc[nc * 2 + 1], cs_sum);
    }
}

// Combine the 5 scales: prod_s val_s^{w_s}, mean over the 48 (n,c) pairs.
__global__ void finalize_kernel(const float* __restrict__ acc,
                                const float* __restrict__ weights,
                                float* __restrict__ out)
{
    int t = threadIdx.x;  // 64 threads
    float v = 0.f;
    if (t < 48) {
        float prod = 1.f;
#pragma unroll
        for (int s = 0; s < 5; ++s) {
            int O = (512 >> s) - HALO;
            float inv = 1.f / ((float)O * (float)O);
            float ssim = acc[s * 96 + t * 2 + 0] * inv;
            float cs   = acc[s * 96 + t * 2 + 1] * inv;
            float val = (s < 4) ? fmaxf(cs, 0.f) : ssim;  // mcs[:-1] + [ssim]
            prod *= powf(val, weights[s]);
        }
        v = prod;
    }
#pragma unroll
    for (int off = 32; off > 0; off >>= 1) v += __shfl_down(v, off, 64);
    if (t == 0) out[0] = v * (1.f / 48.f);
}

extern "C" void kernel_launch(void* const* d_in, const int* in_sizes, int n_in,
                              void* d_out, int out_size, void* d_ws, size_t ws_size,
                              hipStream_t stream) {
    const float* x = (const float*)d_in[0];       // (16,3,512,512)
    const float* y = (const float*)d_in[1];       // (16,3,512,512)
    const float* weights = (const float*)d_in[3]; // (5,)
    float* out = (float*)d_out;
    float* ws = (float*)d_ws;

    // workspace layout (floats):
    //   [0,480)   : acc[5 scales][48 nc][2]   (ssim_sum, cs_sum)
    //   [512, ..) : downsampled pyramid x/y per scale
    float* acc = ws;
    float* xs1 = ws + 512;
    float* ys1 = xs1 + (size_t)48 * 256 * 256;
    float* xs2 = ys1 + (size_t)48 * 256 * 256;
    float* ys2 = xs2 + (size_t)48 * 128 * 128;
    float* xs3 = ys2 + (size_t)48 * 128 * 128;
    float* ys3 = xs3 + (size_t)48 * 64 * 64;
    float* xs4 = ys3 + (size_t)48 * 64 * 64;
    float* ys4 = xs4 + (size_t)48 * 32 * 32;

    hipMemsetAsync(acc, 0, 480 * sizeof(float), stream);

    dim3 blk(256);
    // grid: (col strips of 64, row chunks of 4*ROWS, nc); 4 indep waves/block.
    // R7: same kernel as R5, more blocks per scale (occupancy was grid-limited).
    // scale 0: ROWS=32 -> dim3(8,4,48) = 1536 blocks (24 waves/CU resident)
    ssim_wave_kernel<<<dim3(8, 4, 48), blk, 0, stream>>>(x, y, xs1, ys1, acc + 0 * 96, 512, 512, 32, 1);
    // scale 1: ROWS=16 -> dim3(4,4,48) = 768 blocks
    ssim_wave_kernel<<<dim3(4, 4, 48), blk, 0, stream>>>(xs1, ys1, xs2, ys2, acc + 1 * 96, 256, 256, 16, 1);
    // scale 2: ROWS=8 -> dim3(2,4,48) = 384 blocks
    ssim_wave_kernel<<<dim3(2, 4, 48), blk, 0, stream>>>(xs2, ys2, xs3, ys3, acc + 2 * 96, 128, 128, 8, 1);
    // scale 3: ROWS=4 -> dim3(1,4,48) = 192 blocks (pool rows 0..63 covered)
    ssim_wave_kernel<<<dim3(1, 4, 48), blk, 0, stream>>>(xs3, ys3, xs4, ys4, acc + 3 * 96, 64, 64, 4, 1);
    // scale 4: ROWS=3 -> dim3(1,2,48) = 96 blocks, no pooling (OH=22 = 8 waves x 3 rows, last short)
    ssim_wave_kernel<<<dim3(1, 2, 48), blk, 0, stream>>>(xs4, ys4, nullptr, nullptr, acc + 4 * 96, 32, 32, 3, 0);

    finalize_kernel<<<dim3(1), dim3(64), 0, stream>>>(acc, weights, out);
}

// Round 8
// 304.330 us; speedup vs baseline: 2.1939x; 1.1544x over previous
//
#include <hip/hip_runtime.h>

#define HALO 10
#define SWD 76   // per-wave staged row width (74 used, padded even)

typedef float v2f __attribute__((ext_vector_type(2)));

// 1D Gaussian, sigma=1.5, 11 taps, normalized (compile-time constants;
// matches the reference's fp32 window to ~1e-7 -- far under threshold)
#define G0 0.00102838f
#define G1 0.00759871f
#define G2 0.03600077f
#define G3 0.10936069f
#define G4 0.21300556f
#define G5 0.26601176f
#define G6 G4
#define G7 G3
#define G8 G2
#define G9 G1
#define G10 G0

// one horizontal tap-pair: packed {x,y} means, squares, and cross term
#define HT(QA, QB, W0, W1)                                           \
    { v2f p0; p0.x = QA.x; p0.y = QB.x;                               \
      hm += p0 * (W0); hs += p0 * p0 * (W0); hc += QA.x * QB.x * (W0);\
      v2f p1; p1.x = QA.y; p1.y = QB.y;                               \
      hm += p1 * (W1); hs += p1 * p1 * (W1); hc += QA.y * QB.y * (W1); }

// One streamed row step. U is a compile-time literal after unroll; CX/CY/HX/HY
// are NAMED scalar registers of one of the two depth-2 prefetch sets.
// Order: pool(row i from regs) -> stage(row i) -> issue loads(row i+2 into the
// same set) -> h-conv(row i from LDS) -> v-shift -> output row i-10.
#define STEP(U, CX, CY, HX, HY)                                           \
  { const int i = ii + (U);                                                \
    if (do_pool && i < poolrows) {                                         \
        float sx2 = CX + __shfl_xor(CX, 1, 64);                            \
        float sy2 = CY + __shfl_xor(CY, 1, 64);                            \
        if ((U) & 1) {                                                     \
            if (par == 0) {                                                \
                const int pr = (r0 + i) >> 1;                              \
                xop[(size_t)pr * Wo + (lane >> 1)] = 0.25f * (prevx + sx2);\
                yop[(size_t)pr * Wo + (lane >> 1)] = 0.25f * (prevy + sy2);\
            }                                                              \
        } else { prevx = sx2; prevy = sy2; }                               \
    }                                                                      \
    myA[lane] = CX; myB[lane] = CY;                                        \
    if (lane < HALO) { myA[64 + lane] = HX; myB[64 + lane] = HY; }         \
    {                                                                      \
        const int rr = min(r0 + i + 2, H - 1);                             \
        const float* rx = xp + (size_t)rr * W;                             \
        const float* ry = yp + (size_t)rr * W;                             \
        CX = rx[cl]; CY = ry[cl];                                          \
        if (lane < HALO) { HX = rx[chalo]; HY = ry[chalo]; }               \
    }                                                                      \
    {                                                                      \
        const v2f* pa = (const v2f*)&myA[e];                               \
        const v2f* pb = (const v2f*)&myB[e];                               \
        const v2f qa0 = pa[0], qa1 = pa[1], qa2 = pa[2],                   \
                  qa3 = pa[3], qa4 = pa[4], qa5 = pa[5];                   \
        const v2f qb0 = pb[0], qb1 = pb[1], qb2 = pb[2],                   \
                  qb3 = pb[3], qb4 = pb[4], qb5 = pb[5];                   \
        v2f hm = {0.f, 0.f}, hs = {0.f, 0.f};                              \
        float hc = 0.f;                                                    \
        HT(qa0, qb0, w2_0,  w2_1)                                          \
        HT(qa1, qb1, w2_2,  w2_3)                                          \
        HT(qa2, qb2, w2_4,  w2_5)                                          \
        HT(qa3, qb3, w2_6,  w2_7)                                          \
        HT(qa4, qb4, w2_8,  w2_9)                                          \
        HT(qa5, qb5, w2_10, w2_11)                                         \
        Hm0=Hm1; Hm1=Hm2; Hm2=Hm3; Hm3=Hm4; Hm4=Hm5; Hm5=Hm6;              \
        Hm6=Hm7; Hm7=Hm8; Hm8=Hm9; Hm9=Hm10; Hm10=hm;                      \
        Hs0=Hs1; Hs1=Hs2; Hs2=Hs3; Hs3=Hs4; Hs4=Hs5; Hs5=Hs6;              \
        Hs6=Hs7; Hs7=Hs8; Hs8=Hs9; Hs9=Hs10; Hs10=hs;                      \
        Hc0=Hc1; Hc1=Hc2; Hc2=Hc3; Hc3=Hc4; Hc4=Hc5; Hc5=Hc6;              \
        Hc6=Hc7; Hc7=Hc8; Hc8=Hc9; Hc9=Hc10; Hc10=hc;                      \
    }                                                                      \
    {                                                                      \
        const int o = i - HALO;                                            \
        if (o >= 0 && o < n_out && colvalid) {                             \
            v2f vm = Hm0*G0; vm += Hm1*G1; vm += Hm2*G2; vm += Hm3*G3;     \
            vm += Hm4*G4; vm += Hm5*G5; vm += Hm6*G6; vm += Hm7*G7;        \
            vm += Hm8*G8; vm += Hm9*G9; vm += Hm10*G10;                    \
            v2f vs = Hs0*G0; vs += Hs1*G1; vs += Hs2*G2; vs += Hs3*G3;     \
            vs += Hs4*G4; vs += Hs5*G5; vs += Hs6*G6; vs += Hs7*G7;        \
            vs += Hs8*G8; vs += Hs9*G9; vs += Hs10*G10;                    \
            float vc = Hc0*G0; vc += Hc1*G1; vc += Hc2*G2; vc += Hc3*G3;   \
            vc += Hc4*G4; vc += Hc5*G5; vc += Hc6*G6; vc += Hc7*G7;        \
            vc += Hc8*G8; vc += Hc9*G9; vc += Hc10*G10;                    \
            const float mx = vm.x, my = vm.y;                              \
            const float mu_x2 = mx*mx, mu_y2 = my*my, mu_xy = mx*my;       \
            const float sxq = vs.x - mu_x2, syq = vs.y - mu_y2;            \
            const float sxyv = vc - mu_xy;                                 \
            const float c1 = 1e-4f, c2 = 9e-4f;                            \
            const float cs = (2.f * sxyv + c2)                             \
                           * __builtin_amdgcn_rcpf(sxq + syq + c2);        \
            const float ssim = (2.f * mu_xy + c1)                          \
                  * __builtin_amdgcn_rcpf(mu_x2 + mu_y2 + c1) * cs;        \
            ssim_sum += ssim; cs_sum += cs;                                \
        }                                                                  \
    }                                                                      \
  }

// Wave-private row-streaming separable SSIM + fused 2x2 avg-pool.
// Depth-2 prefetch: two NAMED scalar register sets alternate by sub-iteration
// parity; unroll factor is 22 (even) so the parity is compile-time -- no
// runtime-indexed locals anywhere (SROA-before-unroll spill, R3/R4/R6 lesson).
// __launch_bounds__ 2nd arg stays 3: (256,4) caps VGPR at 128 -> spill (R6).
__global__ __launch_bounds__(256, 3) void ssim_wave_kernel(
    const float* __restrict__ x, const float* __restrict__ y,
    float* __restrict__ xo, float* __restrict__ yo,
    float* __restrict__ acc, int H, int W, int ROWS, int do_pool)
{
    const int OH = H - HALO, OW = W - HALO;
    const int nc = blockIdx.z;
    const int tid = threadIdx.x;
    const int wave = tid >> 6, lane = tid & 63;
    const int col0 = blockIdx.x * 64;
    const int r0 = (blockIdx.y * 4 + wave) * ROWS;

    const int c = col0 + lane;
    const bool colvalid = (c < OW);
    const int cl = min(c, W - 1);
    const int chalo = min(col0 + 64 + lane, W - 1);

    const int n_out = min(ROWS, OH - r0);            // may be <= 0 (pool-only tail)
    const int poolrows = do_pool ? min(ROWS, H - r0) : 0;   // may be negative
    const int n_iter = max(n_out > 0 ? n_out + HALO : 0, poolrows);

    const float* xp = x + (size_t)nc * H * W;
    const float* yp = y + (size_t)nc * H * W;

    __shared__ float sA[4][SWD];
    __shared__ float sB[4][SWD];
    float* myA = sA[wave];
    float* myB = sB[wave];

    // parity-adjusted 12-tap weights as named scalars
    const int par = lane & 1;
    const float w2_0  = par ? 0.f : G0;
    const float w2_1  = par ? G0  : G1;
    const float w2_2  = par ? G1  : G2;
    const float w2_3  = par ? G2  : G3;
    const float w2_4  = par ? G3  : G4;
    const float w2_5  = par ? G4  : G5;
    const float w2_6  = par ? G5  : G6;
    const float w2_7  = par ? G6  : G7;
    const float w2_8  = par ? G7  : G8;
    const float w2_9  = par ? G8  : G9;
    const float w2_10 = par ? G9  : G10;
    const float w2_11 = par ? G10 : 0.f;
    const int e = lane & ~1;

    // vertical shift register (55 named scalars)
    v2f Hm0={0.f,0.f}, Hm1=Hm0, Hm2=Hm0, Hm3=Hm0, Hm4=Hm0, Hm5=Hm0,
        Hm6=Hm0, Hm7=Hm0, Hm8=Hm0, Hm9=Hm0, Hm10=Hm0;
    v2f Hs0=Hm0, Hs1=Hm0, Hs2=Hm0, Hs3=Hm0, Hs4=Hm0, Hs5=Hm0,
        Hs6=Hm0, Hs7=Hm0, Hs8=Hm0, Hs9=Hm0, Hs10=Hm0;
    float Hc0=0.f, Hc1=0.f, Hc2=0.f, Hc3=0.f, Hc4=0.f, Hc5=0.f,
          Hc6=0.f, Hc7=0.f, Hc8=0.f, Hc9=0.f, Hc10=0.f;

    float ssim_sum = 0.f, cs_sum = 0.f;
    float prevx = 0.f, prevy = 0.f;

    // depth-2 prefetch: set0 = even sub-iters, set1 = odd sub-iters
    float ax0 = 0.f, ay0 = 0.f, ahx0 = 0.f, ahy0 = 0.f;
    float ax1 = 0.f, ay1 = 0.f, ahx1 = 0.f, ahy1 = 0.f;

    const int Wo = W >> 1;
    float* xop = xo + (size_t)nc * (H >> 1) * Wo + (col0 >> 1);
    float* yop = yo + (size_t)nc * (H >> 1) * Wo + (col0 >> 1);

    if (n_iter > 0) {
        {   // prologue: rows r0 -> set0, r0+1 -> set1
            const float* rx0 = xp + (size_t)r0 * W;
            const float* ry0 = yp + (size_t)r0 * W;
            const int r1 = min(r0 + 1, H - 1);
            const float* rx1 = xp + (size_t)r1 * W;
            const float* ry1 = yp + (size_t)r1 * W;
            ax0 = rx0[cl]; ay0 = ry0[cl];
            ax1 = rx1[cl]; ay1 = ry1[cl];
            if (lane < HALO) {
                ahx0 = rx0[chalo]; ahy0 = ry0[chalo];
                ahx1 = rx1[chalo]; ahy1 = ry1[chalo];
            }
        }
        const int NI = ((n_iter + 21) / 22) * 22;
        for (int ii = 0; ii < NI; ii += 22) {
#pragma unroll
            for (int u2 = 0; u2 < 11; ++u2) {
                STEP(2 * u2,     ax0, ay0, ahx0, ahy0)
                STEP(2 * u2 + 1, ax1, ay1, ahx1, ahy1)
            }
        }
    }

    // wave-local reduction + one atomic pair per wave
#pragma unroll
    for (int off = 32; off > 0; off >>= 1) {
        ssim_sum += __shfl_down(ssim_sum, off, 64);
        cs_sum   += __shfl_down(cs_sum,   off, 64);
    }
    if (lane == 0) {
        atomicAdd(&acc[nc * 2 + 0], ssim_sum);
        atomicAdd(&acc[nc * 2 + 1], cs_sum);
    }
}

// Combine the 5 scales: prod_s val_s^{w_s}, mean over the 48 (n,c) pairs.
__global__ void finalize_kernel(const float* __restrict__ acc,
                                const float* __restrict__ weights,
                                float* __restrict__ out)
{
    int t = threadIdx.x;  // 64 threads
    float v = 0.f;
    if (t < 48) {
        float prod = 1.f;
#pragma unroll
        for (int s = 0; s < 5; ++s) {
            int O = (512 >> s) - HALO;
            float inv = 1.f / ((float)O * (float)O);
            float ssim = acc[s * 96 + t * 2 + 0] * inv;
            float cs   = acc[s * 96 + t * 2 + 1] * inv;
            float val = (s < 4) ? fmaxf(cs, 0.f) : ssim;  // mcs[:-1] + [ssim]
            prod *= powf(val, weights[s]);
        }
        v = prod;
    }
#pragma unroll
    for (int off = 32; off > 0; off >>= 1) v += __shfl_down(v, off, 64);
    if (t == 0) out[0] = v * (1.f / 48.f);
}

extern "C" void kernel_launch(void* const* d_in, const int* in_sizes, int n_in,
                              void* d_out, int out_size, void* d_ws, size_t ws_size,
                              hipStream_t stream) {
    const float* x = (const float*)d_in[0];       // (16,3,512,512)
    const float* y = (const float*)d_in[1];       // (16,3,512,512)
    const float* weights = (const float*)d_in[3]; // (5,)
    float* out = (float*)d_out;
    float* ws = (float*)d_ws;

    // workspace layout (floats):
    //   [0,480)   : acc[5 scales][48 nc][2]   (ssim_sum, cs_sum)
    //   [512, ..) : downsampled pyramid x/y per scale
    float* acc = ws;
    float* xs1 = ws + 512;
    float* ys1 = xs1 + (size_t)48 * 256 * 256;
    float* xs2 = ys1 + (size_t)48 * 256 * 256;
    float* ys2 = xs2 + (size_t)48 * 128 * 128;
    float* xs3 = ys2 + (size_t)48 * 128 * 128;
    float* ys3 = xs3 + (size_t)48 * 64 * 64;
    float* xs4 = ys3 + (size_t)48 * 64 * 64;
    float* ys4 = xs4 + (size_t)48 * 32 * 32;

    hipMemsetAsync(acc, 0, 480 * sizeof(float), stream);

    dim3 blk(256);
    // grid: (col strips of 64, row chunks of 4*ROWS, nc); 4 indep waves/block.
    // ROWS chosen so interior n_iter (ROWS+10) is a multiple of 22 (no NI waste).
    // scale 0: ROWS=56 -> n_iter=66; y=3 covers 672 rows; 1152 blocks
    ssim_wave_kernel<<<dim3(8, 3, 48), blk, 0, stream>>>(x, y, xs1, ys1, acc + 0 * 96, 512, 512, 56, 1);
    // scale 1: ROWS=34 -> n_iter=44; y=2 covers 272; 384 blocks
    ssim_wave_kernel<<<dim3(4, 2, 48), blk, 0, stream>>>(xs1, ys1, xs2, ys2, acc + 1 * 96, 256, 256, 34, 1);
    // scale 2: ROWS=12 -> n_iter=22; y=3 covers 144; 288 blocks
    ssim_wave_kernel<<<dim3(2, 3, 48), blk, 0, stream>>>(xs2, ys2, xs3, ys3, acc + 2 * 96, 128, 128, 12, 1);
    // scale 3: ROWS=12, y=2 covers 96; 96 blocks
    ssim_wave_kernel<<<dim3(1, 2, 48), blk, 0, stream>>>(xs3, ys3, xs4, ys4, acc + 3 * 96, 64, 64, 12, 1);
    // scale 4: ROWS=12, y=1 (waves 0,1 cover OH=22; 2,3 idle); 48 blocks, no pool
    ssim_wave_kernel<<<dim3(1, 1, 48), blk, 0, stream>>>(xs4, ys4, nullptr, nullptr, acc + 4 * 96, 32, 32, 12, 0);

    finalize_kernel<<<dim3(1), dim3(64), 0, stream>>>(acc, weights, out);
}